// Round 2
// baseline (218.380 us; speedup 1.0000x reference)
//
#include <hip/hip_runtime.h>

// Elementwise 16-step SNN scan, memory-latency-optimized.
// Math identical to R0 (bit-exact vs fp32 reference):
//   v = |x|; z = 0; acc = 0
//   per step: v = fmaf(-z,h[t],v); z = (v > T[t]); acc = fmaf(z,d[t],acc)
//   out = acc * sign(x)  (= sign-bit xor; 0 if x==0)
// R1 changes: 4x float4 per thread per iter + depth-1 software pipeline
// (4-8 loads in flight/wave), nontemporal stores (keep x resident in L3).

typedef float f32x4 __attribute__((ext_vector_type(4)));

__device__ __forceinline__ float snn_elem(float xe,
                                          const float* __restrict__ hh,
                                          const float* __restrict__ dd,
                                          const float* __restrict__ TT) {
    float v = fabsf(xe);
    // t = 0 peeled: z starts at 0.
    float z   = (v > TT[0]) ? 1.0f : 0.0f;
    float acc = z * dd[0];
#pragma unroll
    for (int t = 1; t < 16; ++t) {
        v   = fmaf(-z, hh[t], v);           // exact: z in {0,1}
        z   = (v > TT[t]) ? 1.0f : 0.0f;
        acc = fmaf(z, dd[t], acc);          // exact product, one rounding
    }
    // acc * sign(xe): flip sign bit if xe<0; zero if xe==0.
    unsigned ai = __float_as_uint(acc) ^ (__float_as_uint(xe) & 0x80000000u);
    float r = __uint_as_float(ai);
    return (xe == 0.0f) ? 0.0f : r;
}

__device__ __forceinline__ f32x4 snn_vec4(f32x4 xv,
                                          const float* __restrict__ hh,
                                          const float* __restrict__ dd,
                                          const float* __restrict__ TT) {
    f32x4 ov;
#pragma unroll
    for (int e = 0; e < 4; ++e) ov[e] = snn_elem(xv[e], hh, dd, TT);
    return ov;
}

__global__ __launch_bounds__(256) void snn_scan_kernel(
    const float* __restrict__ x,
    const float* __restrict__ h,
    const float* __restrict__ d,
    const float* __restrict__ T,
    float* __restrict__ out,
    int n4, int n4_full, int n) {
    // Wave-uniform constant-index loads -> SGPRs.
    float hh[16], dd[16], TT[16];
#pragma unroll
    for (int t = 0; t < 16; ++t) { hh[t] = h[t]; dd[t] = d[t]; TT[t] = T[t]; }

    const f32x4* __restrict__ x4 = (const f32x4*)x;
    f32x4* __restrict__ o4       = (f32x4*)out;

    const int tid  = blockIdx.x * blockDim.x + threadIdx.x;
    const int nt   = gridDim.x * blockDim.x;   // total threads
    const int step = nt * 4;                   // float4s per full iteration

    // Main region: n4_full is a multiple of step (computed on host).
    int base = tid;
    if (base < n4_full) {
        f32x4 c0 = x4[base];
        f32x4 c1 = x4[base + nt];
        f32x4 c2 = x4[base + 2 * nt];
        f32x4 c3 = x4[base + 3 * nt];
        int nb = base + step;
        for (; nb < n4_full; nb += step) {
            // Issue next iteration's loads before computing current.
            f32x4 p0 = x4[nb];
            f32x4 p1 = x4[nb + nt];
            f32x4 p2 = x4[nb + 2 * nt];
            f32x4 p3 = x4[nb + 3 * nt];
            __builtin_nontemporal_store(snn_vec4(c0, hh, dd, TT), o4 + base);
            __builtin_nontemporal_store(snn_vec4(c1, hh, dd, TT), o4 + base + nt);
            __builtin_nontemporal_store(snn_vec4(c2, hh, dd, TT), o4 + base + 2 * nt);
            __builtin_nontemporal_store(snn_vec4(c3, hh, dd, TT), o4 + base + 3 * nt);
            c0 = p0; c1 = p1; c2 = p2; c3 = p3;
            base = nb;
        }
        __builtin_nontemporal_store(snn_vec4(c0, hh, dd, TT), o4 + base);
        __builtin_nontemporal_store(snn_vec4(c1, hh, dd, TT), o4 + base + nt);
        __builtin_nontemporal_store(snn_vec4(c2, hh, dd, TT), o4 + base + 2 * nt);
        __builtin_nontemporal_store(snn_vec4(c3, hh, dd, TT), o4 + base + 3 * nt);
    }

    // float4 tail (region not covered by full iterations).
    for (int i = n4_full + tid; i < n4; i += nt) {
        __builtin_nontemporal_store(snn_vec4(x4[i], hh, dd, TT), o4 + i);
    }
    // scalar tail (n % 4) — empty for the bench shape.
    for (int i = n4 * 4 + tid; i < n; i += nt) {
        out[i] = snn_elem(x[i], hh, dd, TT);
    }
}

extern "C" void kernel_launch(void* const* d_in, const int* in_sizes, int n_in,
                              void* d_out, int out_size, void* d_ws, size_t ws_size,
                              hipStream_t stream) {
    const float* x = (const float*)d_in[0];
    const float* h = (const float*)d_in[1];
    const float* d = (const float*)d_in[2];
    const float* T = (const float*)d_in[3];
    float* out     = (float*)d_out;

    const int n  = in_sizes[0];
    const int n4 = n / 4;

    const int block = 256;
    int grid = 2048;  // 256 CU x 8 blocks/CU (full wave-slot capacity)
    const int needed = (n4 + block - 1) / block;
    if (grid > needed) grid = needed > 0 ? needed : 1;

    const int nt      = grid * block;
    const int step    = nt * 4;
    const int n4_full = (n4 / step) * step;

    snn_scan_kernel<<<grid, block, 0, stream>>>(x, h, d, T, out, n4, n4_full, n);
}

// Round 3
// 141.996 us; speedup vs baseline: 1.5379x; 1.5379x over previous
//
#include <hip/hip_runtime.h>

// Elementwise 16-step SNN scan. Math identical to R0 (bit-exact vs fp32 ref):
//   v = |x|; z = 0; acc = 0
//   per step: v = fmaf(-z,h[t],v); z = (v > T[t]); acc = fmaf(z,d[t],acc)
//   out = acc * sign(x)
// R2 change vs R0 (single change): depth-1 software prefetch of the next
// float4 in the grid-stride loop -> 2 loads in flight per wave instead of 1.
// Regular stores (R1's nontemporal stores + 4-stream restructure regressed).

__device__ __forceinline__ float snn_elem(float xe,
                                          const float* __restrict__ hh,
                                          const float* __restrict__ dd,
                                          const float* __restrict__ TT) {
    float v = fabsf(xe);
    // t = 0 peeled: z starts at 0.
    float z   = (v > TT[0]) ? 1.0f : 0.0f;
    float acc = z * dd[0];
#pragma unroll
    for (int t = 1; t < 16; ++t) {
        v   = fmaf(-z, hh[t], v);           // exact: z in {0,1}
        z   = (v > TT[t]) ? 1.0f : 0.0f;
        acc = fmaf(z, dd[t], acc);          // exact product, one rounding
    }
    float s = (xe > 0.0f) ? 1.0f : ((xe < 0.0f) ? -1.0f : 0.0f);
    return acc * s;
}

__device__ __forceinline__ float4 snn_vec4(float4 xv,
                                           const float* __restrict__ hh,
                                           const float* __restrict__ dd,
                                           const float* __restrict__ TT) {
    float4 ov;
    ov.x = snn_elem(xv.x, hh, dd, TT);
    ov.y = snn_elem(xv.y, hh, dd, TT);
    ov.z = snn_elem(xv.z, hh, dd, TT);
    ov.w = snn_elem(xv.w, hh, dd, TT);
    return ov;
}

__global__ __launch_bounds__(256) void snn_scan_kernel(
    const float* __restrict__ x,
    const float* __restrict__ h,
    const float* __restrict__ d,
    const float* __restrict__ T,
    float* __restrict__ out,
    int n4, int n) {
    // Wave-uniform constant-index loads -> SGPRs.
    float hh[16], dd[16], TT[16];
#pragma unroll
    for (int t = 0; t < 16; ++t) { hh[t] = h[t]; dd[t] = d[t]; TT[t] = T[t]; }

    const float4* __restrict__ x4 = reinterpret_cast<const float4*>(x);
    float4* __restrict__ o4       = reinterpret_cast<float4*>(out);

    const int tid = blockIdx.x * blockDim.x + threadIdx.x;
    const int nt  = gridDim.x * blockDim.x;

    int i = tid;
    if (i < n4) {
        float4 cur = x4[i];
        int nx = i + nt;
        while (nx < n4) {
            float4 nxt = x4[nx];            // prefetch next iteration's data
            o4[i] = snn_vec4(cur, hh, dd, TT);
            cur = nxt;
            i = nx;
            nx += nt;
        }
        o4[i] = snn_vec4(cur, hh, dd, TT);
    }

    // Scalar tail (n % 4) — empty for the bench shape.
    for (int j = n4 * 4 + tid; j < n; j += nt) {
        out[j] = snn_elem(x[j], hh, dd, TT);
    }
}

extern "C" void kernel_launch(void* const* d_in, const int* in_sizes, int n_in,
                              void* d_out, int out_size, void* d_ws, size_t ws_size,
                              hipStream_t stream) {
    const float* x = (const float*)d_in[0];
    const float* h = (const float*)d_in[1];
    const float* d = (const float*)d_in[2];
    const float* T = (const float*)d_in[3];
    float* out     = (float*)d_out;

    const int n  = in_sizes[0];
    const int n4 = n / 4;

    const int block = 256;
    int grid = 2048;  // 256 CU x 8 blocks/CU; grid-stride covers the rest
    const int needed = (n4 + block - 1) / block;
    if (grid > needed) grid = needed > 0 ? needed : 1;

    snn_scan_kernel<<<grid, block, 0, stream>>>(x, h, d, T, out, n4, n);
}

// Round 4
// 120.199 us; speedup vs baseline: 1.8168x; 1.1813x over previous
//
#include <hip/hip_runtime.h>

// Elementwise 16-step SNN scan, packed-FP32 edition.
// Math identical to reference (bit-exact): per step
//   v = fma(-z, h[t], v); z = (v > T[t]); acc = fma(z, d[t], acc)
// with z in {0,1} (products exact). v_pk_fma_f32 is IEEE-fused per lane.
// R3 change vs R2 (single variable): element-PAIR processing with
// v_pk_fma_f32; (h[t],d[t]) held as SGPR pairs, broadcast via op_sel
// (both lanes read lo half = h, or hi half = d), -z via neg_lo/neg_hi.
// 6 VALU instrs per 2 elements per step instead of 8.

typedef float f32x2 __attribute__((ext_vector_type(2)));

// v -= z * h   (h = LO half of hd, broadcast to both result lanes)
#define PK_FMA_V(vv, zz, hd)                                                   \
  asm("v_pk_fma_f32 %0, %1, %2, %0 op_sel_hi:[1,0,1] neg_lo:[1,0,0] "          \
      "neg_hi:[1,0,0]"                                                         \
      : "+v"(vv)                                                               \
      : "v"(zz), "s"(hd))

// acc += z * d (d = HI half of hd, broadcast to both result lanes)
#define PK_FMA_A(aa, zz, hd)                                                   \
  asm("v_pk_fma_f32 %0, %1, %2, %0 op_sel:[0,1,0] op_sel_hi:[1,1,1]"           \
      : "+v"(aa)                                                               \
      : "v"(zz), "s"(hd))

__device__ __forceinline__ f32x2 snn_pair(f32x2 xin,
                                          const f32x2* __restrict__ hd2,
                                          const float* __restrict__ TT) {
    f32x2 v, z, acc;
    v.x = fabsf(xin.x);
    v.y = fabsf(xin.y);
    // step 0: z_prev = 0 so v is unchanged; z0 = (v > T[0]); acc = z0*d[0]
    z.x = (v.x > TT[0]) ? 1.0f : 0.0f;
    z.y = (v.y > TT[0]) ? 1.0f : 0.0f;
    acc.x = 0.0f;
    acc.y = 0.0f;
    PK_FMA_A(acc, z, hd2[0]);
#pragma unroll
    for (int t = 1; t < 16; ++t) {
        PK_FMA_V(v, z, hd2[t]);             // v -= z_prev * h[t]
        z.x = (v.x > TT[t]) ? 1.0f : 0.0f;  // z_t = (v > T[t])
        z.y = (v.y > TT[t]) ? 1.0f : 0.0f;
        PK_FMA_A(acc, z, hd2[t]);           // acc += z_t * d[t]
    }
    // out = acc * sign(x): xor sign bit; exact; 0 if x == 0. (verified R1)
    f32x2 r;
    unsigned rx = __float_as_uint(acc.x) ^ (__float_as_uint(xin.x) & 0x80000000u);
    unsigned ry = __float_as_uint(acc.y) ^ (__float_as_uint(xin.y) & 0x80000000u);
    r.x = (xin.x == 0.0f) ? 0.0f : __uint_as_float(rx);
    r.y = (xin.y == 0.0f) ? 0.0f : __uint_as_float(ry);
    return r;
}

__global__ __launch_bounds__(256) void snn_scan_kernel(
    const float* __restrict__ x,
    const float* __restrict__ h,
    const float* __restrict__ d,
    const float* __restrict__ T,
    float* __restrict__ out,
    int n4, int n) {
    // Wave-uniform constants: (h,d) as f32x2 -> SGPR pairs for the pk asm.
    f32x2 hd2[16];
    float TT[16];
#pragma unroll
    for (int t = 0; t < 16; ++t) {
        hd2[t].x = h[t];
        hd2[t].y = d[t];
        TT[t]    = T[t];
    }

    const float4* __restrict__ x4 = reinterpret_cast<const float4*>(x);
    float4* __restrict__ o4       = reinterpret_cast<float4*>(out);

    const int tid = blockIdx.x * blockDim.x + threadIdx.x;
    const int nt  = gridDim.x * blockDim.x;

    int i = tid;
    if (i < n4) {
        float4 cur = x4[i];
        int nx = i + nt;
        while (nx < n4) {
            float4 nxt = x4[nx];  // depth-1 prefetch (kept from R2)
            f32x2 p0 = {cur.x, cur.y}, p1 = {cur.z, cur.w};
            f32x2 r0 = snn_pair(p0, hd2, TT);
            f32x2 r1 = snn_pair(p1, hd2, TT);
            float4 ov = {r0.x, r0.y, r1.x, r1.y};
            o4[i] = ov;
            cur = nxt;
            i = nx;
            nx += nt;
        }
        f32x2 p0 = {cur.x, cur.y}, p1 = {cur.z, cur.w};
        f32x2 r0 = snn_pair(p0, hd2, TT);
        f32x2 r1 = snn_pair(p1, hd2, TT);
        float4 ov = {r0.x, r0.y, r1.x, r1.y};
        o4[i] = ov;
    }

    // Scalar tail (n % 4) — empty for the bench shape.
    for (int j = n4 * 4 + tid; j < n; j += nt) {
        float xe = x[j];
        float v = fabsf(xe);
        float zz = (v > TT[0]) ? 1.0f : 0.0f;
        float acc = zz * d[0];
#pragma unroll
        for (int t = 1; t < 16; ++t) {
            v   = fmaf(-zz, h[t], v);
            zz  = (v > TT[t]) ? 1.0f : 0.0f;
            acc = fmaf(zz, d[t], acc);
        }
        unsigned ri = __float_as_uint(acc) ^ (__float_as_uint(xe) & 0x80000000u);
        out[j] = (xe == 0.0f) ? 0.0f : __uint_as_float(ri);
    }
}

extern "C" void kernel_launch(void* const* d_in, const int* in_sizes, int n_in,
                              void* d_out, int out_size, void* d_ws, size_t ws_size,
                              hipStream_t stream) {
    const float* x = (const float*)d_in[0];
    const float* h = (const float*)d_in[1];
    const float* d = (const float*)d_in[2];
    const float* T = (const float*)d_in[3];
    float* out     = (float*)d_out;

    const int n  = in_sizes[0];
    const int n4 = n / 4;

    const int block = 256;
    int grid = 2048;  // 256 CU x 8 blocks/CU; grid-stride covers the rest
    const int needed = (n4 + block - 1) / block;
    if (grid > needed) grid = needed > 0 ? needed : 1;

    snn_scan_kernel<<<grid, block, 0, stream>>>(x, h, d, T, out, n4, n);
}

// Round 5
// 118.146 us; speedup vs baseline: 1.8484x; 1.0174x over previous
//
#include <hip/hip_runtime.h>

// Elementwise 16-step SNN scan, packed-FP32 (R3 math, bit-exact vs fp32 ref):
//   v = fma(-z,h[t],v); z = (v > T[t]); acc = fma(z,d[t],acc); out = acc*sign(x)
// R4 change vs R3 (single structural variable): 8 elements per thread per
// iteration as TWO ADJACENT float4s (32B contiguous per lane -> 2KB
// contiguous per wave per load), both prefetched one iteration ahead.
// 4 independent pk-chains of ILP; 2-4 loads in flight per wave.

typedef float f32x2 __attribute__((ext_vector_type(2)));

// v -= z * h   (h = LO half of hd, broadcast to both result lanes)
#define PK_FMA_V(vv, zz, hd)                                                   \
  asm("v_pk_fma_f32 %0, %1, %2, %0 op_sel_hi:[1,0,1] neg_lo:[1,0,0] "          \
      "neg_hi:[1,0,0]"                                                         \
      : "+v"(vv)                                                               \
      : "v"(zz), "s"(hd))

// acc += z * d (d = HI half of hd, broadcast to both result lanes)
#define PK_FMA_A(aa, zz, hd)                                                   \
  asm("v_pk_fma_f32 %0, %1, %2, %0 op_sel:[0,1,0] op_sel_hi:[1,1,1]"           \
      : "+v"(aa)                                                               \
      : "v"(zz), "s"(hd))

__device__ __forceinline__ f32x2 snn_pair(f32x2 xin,
                                          const f32x2* __restrict__ hd2,
                                          const float* __restrict__ TT) {
    f32x2 v, z, acc;
    v.x = fabsf(xin.x);
    v.y = fabsf(xin.y);
    z.x = (v.x > TT[0]) ? 1.0f : 0.0f;
    z.y = (v.y > TT[0]) ? 1.0f : 0.0f;
    acc.x = 0.0f;
    acc.y = 0.0f;
    PK_FMA_A(acc, z, hd2[0]);
#pragma unroll
    for (int t = 1; t < 16; ++t) {
        PK_FMA_V(v, z, hd2[t]);             // v -= z_prev * h[t]  (exact)
        z.x = (v.x > TT[t]) ? 1.0f : 0.0f;
        z.y = (v.y > TT[t]) ? 1.0f : 0.0f;
        PK_FMA_A(acc, z, hd2[t]);           // acc += z_t * d[t]   (exact)
    }
    f32x2 r;
    unsigned rx = __float_as_uint(acc.x) ^ (__float_as_uint(xin.x) & 0x80000000u);
    unsigned ry = __float_as_uint(acc.y) ^ (__float_as_uint(xin.y) & 0x80000000u);
    r.x = (xin.x == 0.0f) ? 0.0f : __uint_as_float(rx);
    r.y = (xin.y == 0.0f) ? 0.0f : __uint_as_float(ry);
    return r;
}

__device__ __forceinline__ float4 snn_vec4(float4 cur,
                                           const f32x2* __restrict__ hd2,
                                           const float* __restrict__ TT) {
    f32x2 p0 = {cur.x, cur.y}, p1 = {cur.z, cur.w};
    f32x2 r0 = snn_pair(p0, hd2, TT);
    f32x2 r1 = snn_pair(p1, hd2, TT);
    float4 ov = {r0.x, r0.y, r1.x, r1.y};
    return ov;
}

__global__ __launch_bounds__(256) void snn_scan_kernel(
    const float* __restrict__ x,
    const float* __restrict__ h,
    const float* __restrict__ d,
    const float* __restrict__ T,
    float* __restrict__ out,
    int n8, int n4, int n) {
    // Wave-uniform constants: (h,d) as f32x2 -> SGPR pairs for the pk asm.
    f32x2 hd2[16];
    float TT[16];
#pragma unroll
    for (int t = 0; t < 16; ++t) {
        hd2[t].x = h[t];
        hd2[t].y = d[t];
        TT[t]    = T[t];
    }

    const float4* __restrict__ x4 = reinterpret_cast<const float4*>(x);
    float4* __restrict__ o4       = reinterpret_cast<float4*>(out);

    const int tid = blockIdx.x * blockDim.x + threadIdx.x;
    const int nt  = gridDim.x * blockDim.x;

    // Main region: thread i owns float4 indices {2i, 2i+1} then strides 2*nt.
    int i = tid;                 // unit = pair-of-float4
    if (i < n8) {
        float4 ca = x4[2 * i];
        float4 cb = x4[2 * i + 1];
        int nx = i + nt;
        while (nx < n8) {
            float4 pa = x4[2 * nx];         // prefetch next iteration (32B
            float4 pb = x4[2 * nx + 1];     // contiguous per lane)
            o4[2 * i]     = snn_vec4(ca, hd2, TT);
            o4[2 * i + 1] = snn_vec4(cb, hd2, TT);
            ca = pa;
            cb = pb;
            i = nx;
            nx += nt;
        }
        o4[2 * i]     = snn_vec4(ca, hd2, TT);
        o4[2 * i + 1] = snn_vec4(cb, hd2, TT);
    }

    // float4 tail (n4 not covered by pairs).
    for (int j = n8 * 2 + tid; j < n4; j += nt) {
        o4[j] = snn_vec4(x4[j], hd2, TT);
    }
    // scalar tail (n % 4) — empty for the bench shape.
    for (int j = n4 * 4 + tid; j < n; j += nt) {
        float xe = x[j];
        float v = fabsf(xe);
        float zz = (v > TT[0]) ? 1.0f : 0.0f;
        float acc = zz * d[0];
#pragma unroll
        for (int t = 1; t < 16; ++t) {
            v   = fmaf(-zz, h[t], v);
            zz  = (v > TT[t]) ? 1.0f : 0.0f;
            acc = fmaf(zz, d[t], acc);
        }
        unsigned ri = __float_as_uint(acc) ^ (__float_as_uint(xe) & 0x80000000u);
        out[j] = (xe == 0.0f) ? 0.0f : __uint_as_float(ri);
    }
}

extern "C" void kernel_launch(void* const* d_in, const int* in_sizes, int n_in,
                              void* d_out, int out_size, void* d_ws, size_t ws_size,
                              hipStream_t stream) {
    const float* x = (const float*)d_in[0];
    const float* h = (const float*)d_in[1];
    const float* d = (const float*)d_in[2];
    const float* T = (const float*)d_in[3];
    float* out     = (float*)d_out;

    const int n  = in_sizes[0];
    const int n4 = n / 4;
    const int n8 = n / 8;   // pair-of-float4 units

    const int block = 256;
    int grid = 2048;  // 256 CU x 8 blocks/CU = exactly 32 waves/CU capacity
    const int needed = (n8 + block - 1) / block;
    if (grid > needed) grid = needed > 0 ? needed : 1;

    snn_scan_kernel<<<grid, block, 0, stream>>>(x, h, d, T, out, n8, n4, n);
}